// Round 21
// baseline (135.237 us; speedup 1.0000x reference)
//
#include <hip/hip_runtime.h>

#define ND 2048
#define NM 512
#define DIN 256
#define OC 128
#define NTOT 2560
#define NE 513      // slots per hyperedge

// Workspace float offsets. Dirty footprint ~2 MB.
#define WS_PARTC 0                          // [256*256]
#define WS_PARTM (WS_PARTC + 256*256)       // [64*256]
#define WS_AHE   (WS_PARTM + 64*256)        // [2048]
#define WS_ANODE (WS_AHE + ND)              // [2560]
#define WS_CD    (WS_ANODE + NTOT)          // [2048]
#define WS_XLIN  (WS_CD + ND)               // [2048*128] disease x_lin (f32)
#define WS_DIA   (WS_XLIN + ND*OC)          // [128]
#define WS_MED   (WS_DIA + OC)              // [128]
#define WS_XM16  (WS_MED + OC)              // [512*128 u16 = 32768 floats]
#define WS_E16   (WS_XM16 + NM*OC/2)        // [2048*128 u16 = 131072 floats]

typedef unsigned short u16;
typedef unsigned int u32;

__device__ __forceinline__ float lrelu(float x) { return x > 0.f ? x : 0.2f * x; }
__device__ __forceinline__ u16 f2b(float f) {
    u32 x = __float_as_uint(f);
    return (u16)((x + 0x7fffu + ((x >> 16) & 1u)) >> 16);
}
__device__ __forceinline__ float bfl(u32 u) { return __uint_as_float(u << 16); }
__device__ __forceinline__ float bfh(u32 u) { return __uint_as_float(u & 0xffff0000u); }

// ---------------------------------------------------------------------------
// K1: blocks 0..255: disease x_lin (8 rows, f32) + a_node + mean partials.
//     blocks 256..319: medicine x_lin -> bf16 Xm16 + a_node + mean partials.
//     blocks 320..383: w_e (redundant) + a_he (32 d's each).
__global__ void __launch_bounds__(256) K1(
        const float* __restrict__ c_emb, const float* __restrict__ m_emb,
        const float* __restrict__ W_gat, const float* __restrict__ att,
        const float* __restrict__ he_attr, float* __restrict__ ws) {
    const int b = blockIdx.x, t = threadIdx.x;
    if (b < 320) {
        __shared__ float row[8][DIN];
        __shared__ float sA[8][OC];
        const int d0 = b * 8;
#pragma unroll
        for (int p = 0; p < 4; ++p) {
            const int idx = p * 256 + t;
            const int r = idx >> 7, c = idx & 127;
            const int d = d0 + r;
            const float* src = (d < ND) ? c_emb + (size_t)d * DIN
                                        : m_emb + (size_t)(d - ND) * DIN;
            const float2 u = ((const float2*)src)[c];
            row[r][2 * c]     = u.x;
            row[r][2 * c + 1] = u.y;
        }
        __syncthreads();
        {
            float pc = 0.f;
#pragma unroll
            for (int r = 0; r < 8; ++r) pc += row[r][t];
            if (b < 256) ws[WS_PARTC + b * 256 + t] = pc;
            else         ws[WS_PARTM + (b - 256) * 256 + t] = pc;
        }
        const int o = t & (OC - 1), h = t >> 7;
        float a0 = 0.f, a1 = 0.f, a2 = 0.f, a3 = 0.f;
        const float4* wr  = (const float4*)(W_gat + (size_t)o * DIN);
        const float4* r0v = (const float4*)(row[4 * h]);
        const float4* r1v = (const float4*)(row[4 * h + 1]);
        const float4* r2v = (const float4*)(row[4 * h + 2]);
        const float4* r3v = (const float4*)(row[4 * h + 3]);
#pragma unroll 4
        for (int v = 0; v < 64; ++v) {
            const float4 w  = wr[v];
            const float4 x0 = r0v[v], x1 = r1v[v], x2 = r2v[v], x3 = r3v[v];
            a0 = fmaf(x0.x, w.x, a0); a0 = fmaf(x0.y, w.y, a0);
            a0 = fmaf(x0.z, w.z, a0); a0 = fmaf(x0.w, w.w, a0);
            a1 = fmaf(x1.x, w.x, a1); a1 = fmaf(x1.y, w.y, a1);
            a1 = fmaf(x1.z, w.z, a1); a1 = fmaf(x1.w, w.w, a1);
            a2 = fmaf(x2.x, w.x, a2); a2 = fmaf(x2.y, w.y, a2);
            a2 = fmaf(x2.z, w.z, a2); a2 = fmaf(x2.w, w.w, a2);
            a3 = fmaf(x3.x, w.x, a3); a3 = fmaf(x3.y, w.y, a3);
            a3 = fmaf(x3.z, w.z, a3); a3 = fmaf(x3.w, w.w, a3);
        }
        if (b < 256) {
            float* xl = ws + WS_XLIN + (size_t)(d0 + 4 * h) * OC + o;
            xl[0 * OC] = a0; xl[1 * OC] = a1; xl[2 * OC] = a2; xl[3 * OC] = a3;
        } else {
            const int m0 = d0 - ND + 4 * h;
            u16* xm16 = (u16*)(ws + WS_XM16);
            xm16[(size_t)(m0 + 0) * OC + o] = f2b(a0);
            xm16[(size_t)(m0 + 1) * OC + o] = f2b(a1);
            xm16[(size_t)(m0 + 2) * OC + o] = f2b(a2);
            xm16[(size_t)(m0 + 3) * OC + o] = f2b(a3);
        }
        const float at = att[o];
        sA[4 * h][o]     = a0 * at;
        sA[4 * h + 1][o] = a1 * at;
        sA[4 * h + 2][o] = a2 * at;
        sA[4 * h + 3][o] = a3 * at;
        __syncthreads();
#pragma unroll
        for (int st = 64; st >= 1; st >>= 1) {
            for (int idx = t; idx < 8 * st; idx += 256) {
                const int r = idx / st, i = idx - r * st;
                sA[r][i] += sA[r][i + st];
            }
            __syncthreads();
        }
        if (t < 8) ws[WS_ANODE + d0 + t] = sA[t][0];
    } else {
        __shared__ float satt[OC];
        __shared__ float we[DIN];
        const int q = b - 320;
        if (t < OC) satt[t] = att[OC + t];
        __syncthreads();
        float acc = 0.f;
#pragma unroll 8
        for (int o = 0; o < OC; ++o)
            acc = fmaf(W_gat[(size_t)o * DIN + t], satt[o], acc);
        we[t] = acc;
        __syncthreads();
        const int r = t >> 5, l = t & 31;
#pragma unroll
        for (int k = 0; k < 4; ++k) {
            const int d = q * 32 + k * 8 + r;
            const float* he = he_attr + (size_t)d * DIN;
            float ah = 0.f;
#pragma unroll
            for (int i = l; i < DIN; i += 32) ah = fmaf(he[i], we[i], ah);
#pragma unroll
            for (int m = 1; m < 32; m <<= 1) ah += __shfl_xor(ah, m, 32);
            if (l == 0) ws[WS_AHE + d] = ah;
        }
    }
}

// ---------------------------------------------------------------------------
// K2: blocks 0..255: softmax (8 d's) -> alpha, C_d; GEMM over bf16 Xm16;
//     e -> bf16; disease dm half. block 256: mean combine -> dia/med.
__global__ void __launch_bounds__(256) K2(
        const float* __restrict__ W_conv, const float* __restrict__ b_conv,
        const float* __restrict__ b_gat, float* __restrict__ ws,
        float* __restrict__ out) {
    const int b = blockIdx.x, t = threadIdx.x;
    if (b == 256) {
        __shared__ float mc[DIN], mm[DIN];
        float sc = 0.f, sm = 0.f;
        for (int bb = 0; bb < 256; ++bb) sc += ws[WS_PARTC + bb * 256 + t];
        for (int bb = 0; bb < 64;  ++bb) sm += ws[WS_PARTM + bb * 256 + t];
        mc[t] = sc * (1.f / ND);
        mm[t] = sm * (1.f / NM);
        __syncthreads();
        if (t < OC) {
            const float4* wr = (const float4*)(W_conv + (size_t)t * DIN);
            float a = 0.f, m2 = 0.f;
#pragma unroll 8
            for (int v = 0; v < 64; ++v) {
                const float4 w = wr[v];
                const int ib = 4 * v;
                a  = fmaf(mc[ib], w.x, a);      a  = fmaf(mc[ib + 1], w.y, a);
                a  = fmaf(mc[ib + 2], w.z, a);  a  = fmaf(mc[ib + 3], w.w, a);
                m2 = fmaf(mm[ib], w.x, m2);     m2 = fmaf(mm[ib + 1], w.y, m2);
                m2 = fmaf(mm[ib + 2], w.z, m2); m2 = fmaf(mm[ib + 3], w.w, m2);
            }
            const float bc = b_conv[t];
            ws[WS_DIA + t] = a + bc;
            ws[WS_MED + t] = m2 + bc;
        }
        return;
    }
    __shared__ float zbuf[NE][8];        // 16.4 KB
    __shared__ float anm[NM];            // 2 KB
    __shared__ float sacc[16][8][OC];    // 64 KB [slice][k][o]
    anm[t]       = ws[WS_ANODE + ND + t];
    anm[t + 256] = ws[WS_ANODE + ND + 256 + t];
    __syncthreads();
    {
        const int r = t >> 5, l = t & 31;
        const int d = b * 8 + r;
        const float ah = ws[WS_AHE + d];
        const float an_d = ws[WS_ANODE + d];
        float lmax = -3.4e38f;
        for (int j = l; j < NE; j += 32) {
            const float v = (j == 0) ? an_d : anm[j - 1];
            const float lg = lrelu(v + ah);
            zbuf[j][r] = lg;
            lmax = fmaxf(lmax, lg);
        }
#pragma unroll
        for (int m = 1; m < 32; m <<= 1) lmax = fmaxf(lmax, __shfl_xor(lmax, m, 32));
        float ss = 0.f;
        for (int j = l; j < NE; j += 32) {
            const float z = __expf(zbuf[j][r] - lmax);
            zbuf[j][r] = z;
            ss += z;
        }
#pragma unroll
        for (int m = 1; m < 32; m <<= 1) ss += __shfl_xor(ss, m, 32);
        const float inv = 1.f / ss;
        if (l == 0) ws[WS_CD + d] = lmax + __logf(ss);
        for (int j = l; j < NE; j += 32) zbuf[j][r] *= inv;   // -> alpha
    }
    __syncthreads();
    // GEMM over bf16 Xm: thread = (o-oct q: 8 o's, j-slice s: 32 j's)
    {
        const int q = t & 15, s = t >> 4;
        const uint4* xm4 = (const uint4*)((const u16*)(ws + WS_XM16));
        float acc[8][8];
#pragma unroll
        for (int k = 0; k < 8; ++k)
#pragma unroll
            for (int i = 0; i < 8; ++i) acc[k][i] = 0.f;
        const int j0 = s * 32;
#pragma unroll 4
        for (int i = 0; i < 32; ++i) {
            const int j = j0 + i;
            const uint4 u = xm4[(size_t)j * 16 + q];
            float ev[8];
            ev[0] = bfl(u.x); ev[1] = bfh(u.x);
            ev[2] = bfl(u.y); ev[3] = bfh(u.y);
            ev[4] = bfl(u.z); ev[5] = bfh(u.z);
            ev[6] = bfl(u.w); ev[7] = bfh(u.w);
            const float4* zr = (const float4*)zbuf[j + 1];
            const float4 za = zr[0], zb4 = zr[1];
            const float zk[8] = {za.x, za.y, za.z, za.w, zb4.x, zb4.y, zb4.z, zb4.w};
#pragma unroll
            for (int k = 0; k < 8; ++k)
#pragma unroll
                for (int oi = 0; oi < 8; ++oi)
                    acc[k][oi] = fmaf(zk[k], ev[oi], acc[k][oi]);
        }
#pragma unroll
        for (int k = 0; k < 8; ++k)
#pragma unroll
            for (int oi = 0; oi < 8; ++oi) sacc[s][k][q * 8 + oi] = acc[k][oi];
    }
    __syncthreads();
    // epilogue: 16-slice reduce; e -> bf16; disease dm half
    {
        u16* e16 = (u16*)(ws + WS_E16);
        for (int idx = t; idx < 8 * OC; idx += 256) {
            const int k = idx >> 7, o = idx & 127;
            const int dd = b * 8 + k;
            float sum = 0.f;
#pragma unroll
            for (int s2 = 0; s2 < 16; ++s2) sum += sacc[s2][k][o];
            const float a0 = zbuf[0][k];
            const float xown = ws[WS_XLIN + (size_t)dd * OC + o];
            const float ev = fmaf(a0, xown, sum) * (1.f / NE);
            e16[(size_t)dd * OC + o] = f2b(ev);
            out[(size_t)dd * 2 * OC + o] = fmaf(a0, ev, b_gat[o]);
        }
    }
}

// ---------------------------------------------------------------------------
// K3: blocks 0..127: 4 medicines each; e16 uint4 loads (64 MB total L3 reads).
//     blocks 128..191: dia_nf broadcast into disease rows' second half.
__global__ void __launch_bounds__(256) K3(
        const float* __restrict__ b_gat, const float* __restrict__ ws,
        float* __restrict__ out) {
    const int b = blockIdx.x, t = threadIdx.x;
    if (b < 128) {
        __shared__ float zb[ND][4];          // 32 KB alpha
        __shared__ float sacc[16][4][OC];    // 32 KB slice partials
        const int m0 = b * 4;
        float an[4];
#pragma unroll
        for (int k = 0; k < 4; ++k) an[k] = ws[WS_ANODE + ND + m0 + k];
        for (int dd = t; dd < ND; dd += 256) {
            const float ahv = ws[WS_AHE + dd];
            const float cdv = ws[WS_CD + dd];
#pragma unroll
            for (int k = 0; k < 4; ++k)
                zb[dd][k] = __expf(lrelu(an[k] + ahv) - cdv);
        }
        __syncthreads();
        // thread = (o-oct q: 8 o's, d-slice s: 128 d's); 128 uint4 loads
        const int q = t & 15, s = t >> 4;
        const uint4* e4 = (const uint4*)((const u16*)(ws + WS_E16));
        float A[4][8];
#pragma unroll
        for (int k = 0; k < 4; ++k)
#pragma unroll
            for (int i = 0; i < 8; ++i) A[k][i] = 0.f;
        const int dd0 = s * 128;
#pragma unroll 4
        for (int i = 0; i < 128; ++i) {
            const int dd = dd0 + i;
            const uint4 u = e4[(size_t)dd * 16 + q];
            float ev[8];
            ev[0] = bfl(u.x); ev[1] = bfh(u.x);
            ev[2] = bfl(u.y); ev[3] = bfh(u.y);
            ev[4] = bfl(u.z); ev[5] = bfh(u.z);
            ev[6] = bfl(u.w); ev[7] = bfh(u.w);
            const float4 zq = *(const float4*)zb[dd];
            const float zk[4] = {zq.x, zq.y, zq.z, zq.w};
#pragma unroll
            for (int k = 0; k < 4; ++k)
#pragma unroll
                for (int oi = 0; oi < 8; ++oi)
                    A[k][oi] = fmaf(zk[k], ev[oi], A[k][oi]);
        }
#pragma unroll
        for (int k = 0; k < 4; ++k)
#pragma unroll
            for (int oi = 0; oi < 8; ++oi) sacc[s][k][q * 8 + oi] = A[k][oi];
        __syncthreads();
        // reduce: 512 (med,o) outputs over 256 threads
        for (int idx = t; idx < 4 * OC; idx += 256) {
            const int med = idx >> 7, o = idx & 127;
            float sum = 0.f;
#pragma unroll
            for (int sl = 0; sl < 16; ++sl) sum += sacc[sl][med][o];
            const int m = m0 + med;
            out[(size_t)(ND + m) * 2 * OC + o]      = fmaf(sum, 1.f / ND, b_gat[o]);
            out[(size_t)(ND + m) * 2 * OC + OC + o] = ws[WS_MED + o];
        }
    } else {
        const int q2 = b - 128;
        const int o = t & (OC - 1), h = t >> 7;
        const float dv = ws[WS_DIA + o];
#pragma unroll
        for (int rr = 0; rr < 16; ++rr) {
            const int d = q2 * 32 + 2 * rr + h;
            out[(size_t)d * 2 * OC + OC + o] = dv;
        }
    }
}

extern "C" void kernel_launch(void* const* d_in, const int* in_sizes, int n_in,
                              void* d_out, int out_size, void* d_ws, size_t ws_size,
                              hipStream_t stream) {
    const float* c_emb   = (const float*)d_in[2];
    const float* m_emb   = (const float*)d_in[3];
    const float* W_conv  = (const float*)d_in[4];
    const float* b_conv  = (const float*)d_in[5];
    const float* W_gat   = (const float*)d_in[6];
    const float* att     = (const float*)d_in[7];
    const float* b_gat   = (const float*)d_in[8];
    const float* he_attr = (const float*)d_in[9];
    float* ws  = (float*)d_ws;
    float* out = (float*)d_out;

    hipLaunchKernelGGL(K1, dim3(384), dim3(256), 0, stream,
                       c_emb, m_emb, W_gat, att, he_attr, ws);
    hipLaunchKernelGGL(K2, dim3(257), dim3(256), 0, stream,
                       W_conv, b_conv, b_gat, ws, out);
    hipLaunchKernelGGL(K3, dim3(192), dim3(256), 0, stream, b_gat, ws, out);
}